// Round 1
// baseline (120.977 us; speedup 1.0000x reference)
//
#include <hip/hip_runtime.h>
#include <math.h>

// Problem constants (fixed by setup_inputs): N=32768, B=32, S=1024, H=512, OUT=32.
#define H_DIM   512
#define OUT_DIM 32
#define S_LEN   1024
#define TOK_PER_BLOCK 64
#define THREADS 256

// Rank-2 collapse of the attention:
//   score(i,j) = scale * x_i^T (Wq Wk^T) x_j          (M is 2x2)
//   out_i      = (softmax-weighted mean of x_j) @ Wv  (w_i is a 2-vector)
// BN folds into A0 = Wv[0]*g, A1 = Wv[1]*g, C = beta - mean*g, g = gamma/sqrt(var+eps).
// Then y_i = PReLU(w0*A0 + w1*A1 + C) @ Wout + bout.

__global__ __launch_bounds__(THREADS)
void fused_attn_kernel(const float* __restrict__ x,
                       const float* __restrict__ Wq,
                       const float* __restrict__ Wk,
                       const float* __restrict__ Wv,
                       const float* __restrict__ bn_gamma,
                       const float* __restrict__ bn_beta,
                       const float* __restrict__ bn_mean,
                       const float* __restrict__ bn_var,
                       const float* __restrict__ prelu_a,
                       const float* __restrict__ Wout,
                       const float* __restrict__ bout,
                       float* __restrict__ out)
{
    __shared__ float2 xs[S_LEN];                      // 8 KB: this batch's x
    __shared__ float As0[H_DIM], As1[H_DIM], Cs[H_DIM]; // 6 KB
    __shared__ float mred[4][4];                      // 2x2 M partials per wave
    __shared__ float redm[4][64];                     // cross-wave max
    __shared__ float redl[4][64], redw0[4][64], redw1[4][64];
    __shared__ float yred[4][64][33];                 // +1 pad: conflict-free transpose

    const int t    = threadIdx.x;
    const int lane = t & 63;
    const int q    = __builtin_amdgcn_readfirstlane(t >> 6);  // wave id, SGPR -> uniform h
    const int b    = blockIdx.x >> 4;   // 16 blocks per batch (1024/64)
    const int tile = blockIdx.x & 15;
    const float scale = 0.044194173824159216f;  // 1/sqrt(512)

    // ---- stage this batch's x into LDS (coalesced float4) ----
    const float4* xg = (const float4*)(x + (size_t)b * (S_LEN * 2));
    float4* xs4 = (float4*)xs;
    xs4[t]       = xg[t];
    xs4[t + 256] = xg[t + 256];

    // ---- fold BN into Wv ----
    #pragma unroll
    for (int k = 0; k < 2; ++k) {
        int h = t + k * 256;
        float g = bn_gamma[h] * rsqrtf(bn_var[h] + 1e-5f);
        As0[h] = Wv[h] * g;
        As1[h] = Wv[H_DIM + h] * g;
        Cs[h]  = bn_beta[h] - bn_mean[h] * g;
    }

    // ---- M = Wq Wk^T (2x2), block-wide reduction ----
    float m00 = 0.f, m01 = 0.f, m10 = 0.f, m11 = 0.f;
    #pragma unroll
    for (int k = 0; k < 2; ++k) {
        int h = t + k * 256;
        float a0 = Wq[h], a1 = Wq[H_DIM + h];
        float b0 = Wk[h], b1 = Wk[H_DIM + h];
        m00 = fmaf(a0, b0, m00); m01 = fmaf(a0, b1, m01);
        m10 = fmaf(a1, b0, m10); m11 = fmaf(a1, b1, m11);
    }
    #pragma unroll
    for (int off = 32; off >= 1; off >>= 1) {
        m00 += __shfl_xor(m00, off);
        m01 += __shfl_xor(m01, off);
        m10 += __shfl_xor(m10, off);
        m11 += __shfl_xor(m11, off);
    }
    if (lane == 0) { mred[q][0] = m00; mred[q][1] = m01; mred[q][2] = m10; mred[q][3] = m11; }
    __syncthreads();
    m00 = (mred[0][0] + mred[1][0] + mred[2][0] + mred[3][0]) * scale;
    m01 = (mred[0][1] + mred[1][1] + mred[2][1] + mred[3][1]) * scale;
    m10 = (mred[0][2] + mred[1][2] + mred[2][2] + mred[3][2]) * scale;
    m11 = (mred[0][3] + mred[1][3] + mred[2][3] + mred[3][3]) * scale;

    // ---- per-token query vector u = x_i^T M ----
    const float2 xt = xs[tile * TOK_PER_BLOCK + lane];
    const float u0 = fmaf(xt.x, m00, xt.y * m10);
    const float u1 = fmaf(xt.x, m01, xt.y * m11);

    // ---- pass 1: max over this wave's 256-key slice ----
    const int j0 = q * 256;
    float mx = -1e30f;
    for (int j = j0; j < j0 + 256; ++j) {
        float2 xj = xs[j];                       // broadcast read
        float s = fmaf(u0, xj.x, u1 * xj.y);
        mx = fmaxf(mx, s);
    }
    redm[q][lane] = mx;
    __syncthreads();
    mx = fmaxf(fmaxf(redm[0][lane], redm[1][lane]),
               fmaxf(redm[2][lane], redm[3][lane]));

    // ---- pass 2: exp-sum + weighted x accumulation ----
    float l = 0.f, w0 = 0.f, w1 = 0.f;
    for (int j = j0; j < j0 + 256; ++j) {
        float2 xj = xs[j];
        float s = fmaf(u0, xj.x, u1 * xj.y);
        float e = __expf(s - mx);
        l += e;
        w0 = fmaf(e, xj.x, w0);
        w1 = fmaf(e, xj.y, w1);
    }
    redl[q][lane] = l; redw0[q][lane] = w0; redw1[q][lane] = w1;
    __syncthreads();
    l  = redl[0][lane] + redl[1][lane] + redl[2][lane] + redl[3][lane];
    w0 = redw0[0][lane] + redw0[1][lane] + redw0[2][lane] + redw0[3][lane];
    w1 = redw1[0][lane] + redw1[1][lane] + redw1[2][lane] + redw1[3][lane];
    const float inv = 1.0f / l;
    w0 *= inv; w1 *= inv;

    // ---- epilogue: wave q handles h in [q*128, q*128+128), all 32 outputs ----
    // h is wave-uniform (q via readfirstlane) -> Wout reads become s_load.
    const float aprelu = prelu_a[0];
    float y[OUT_DIM];
    #pragma unroll
    for (int o = 0; o < OUT_DIM; ++o) y[o] = 0.f;
    const int h0 = q * 128;
    for (int hh = 0; hh < 128; ++hh) {
        int h = h0 + hh;
        float p = fmaf(w0, As0[h], fmaf(w1, As1[h], Cs[h]));
        p = (p >= 0.f) ? p : aprelu * p;
        const float* wrow = Wout + h * OUT_DIM;
        #pragma unroll
        for (int o = 0; o < OUT_DIM; ++o)
            y[o] = fmaf(p, wrow[o], y[o]);
    }

    // ---- cross-wave y reduction via LDS (padded, conflict-free) ----
    #pragma unroll
    for (int o = 0; o < OUT_DIM; ++o) yred[q][lane][o] = y[o];
    __syncthreads();

    // ---- reduce + bias + coalesced store: 64 tok x 32 out = 2048 floats ----
    const size_t base = (size_t)(b * S_LEN + tile * TOK_PER_BLOCK) * OUT_DIM;
    const float bo = bout[t & 31];
    #pragma unroll
    for (int k = 0; k < 8; ++k) {
        int e = k * 256 + t;          // e = tok*32 + o; e&31 == t&31
        int tok = e >> 5, o = e & 31;
        float v = yred[0][tok][o] + yred[1][tok][o] +
                  yred[2][tok][o] + yred[3][tok][o] + bo;
        out[base + e] = v;
    }
}

extern "C" void kernel_launch(void* const* d_in, const int* in_sizes, int n_in,
                              void* d_out, int out_size, void* d_ws, size_t ws_size,
                              hipStream_t stream) {
    const float* x    = (const float*)d_in[0];
    // d_in[1] = batch_size (int, ==32 for this problem; S = N/32 = 1024 hard-coded)
    const float* Wq   = (const float*)d_in[2];
    const float* Wk   = (const float*)d_in[3];
    const float* Wv   = (const float*)d_in[4];
    const float* gam  = (const float*)d_in[5];
    const float* bet  = (const float*)d_in[6];
    const float* mean = (const float*)d_in[7];
    const float* var  = (const float*)d_in[8];
    const float* pa   = (const float*)d_in[9];
    const float* Wout = (const float*)d_in[10];
    const float* bo   = (const float*)d_in[11];
    float* out = (float*)d_out;

    const int N = in_sizes[0] / 2;          // 32768 tokens
    const int blocks = N / TOK_PER_BLOCK;   // 512
    hipLaunchKernelGGL(fused_attn_kernel, dim3(blocks), dim3(THREADS), 0, stream,
                       x, Wq, Wk, Wv, gam, bet, mean, var, pa, Wout, bo, out);
}